// Round 1
// baseline (526.328 us; speedup 1.0000x reference)
//
#include <hip/hip_runtime.h>
#include <math.h>

#define B 32
#define H 8
#define N 512

// ws float layout: dep[B*H] | oth[B*N] | r0[B*H] | c0[B*H] | r[B*N] | c[B*N] | E0[B*H*N] | Ec[B*H*N]

__global__ __launch_bounds__(256) void k_max_init(const float* __restrict__ in,
                                                  float* __restrict__ dep,
                                                  float* __restrict__ oth,
                                                  float* __restrict__ c0v,
                                                  float* __restrict__ cv,
                                                  float* __restrict__ rv) {
    const int i = blockIdx.x;
    const int b = blockIdx.y;
    const int tid = threadIdx.x;
    __shared__ float red[256];
    if (i > 0) {
        float m = -INFINITY;
        for (int h = 0; h < H; ++h) {
            const float* row = in + (((size_t)(b * H + h) * N + i) * N);
            for (int j = tid; j < N; j += 256) m = fmaxf(m, row[j]);
        }
        red[tid] = m; __syncthreads();
        for (int s = 128; s > 0; s >>= 1) {
            if (tid < s) red[tid] = fmaxf(red[tid], red[tid + s]);
            __syncthreads();
        }
        if (tid == 0) { oth[b * N + i] = red[0]; cv[b * N + i] = 1.0f; }
    } else {
        // per-(b,h) max over row 0; 8 groups of 32 lanes
        const int h = tid >> 5, lane = tid & 31;
        const float* row = in + ((size_t)(b * H + h) * N) * N;  // i = 0
        float m = -INFINITY;
        for (int j = lane; j < N; j += 32) m = fmaxf(m, row[j]);
        for (int s = 16; s > 0; s >>= 1) m = fmaxf(m, __shfl_down(m, s, 32));
        if (lane == 0) { dep[b * H + h] = m; c0v[b * H + h] = 1.0f; }
        if (tid == 0) { cv[b * N] = 1.0f; rv[b * N] = 1.0f; }
    }
}

__global__ __launch_bounds__(256) void k_build(const float* __restrict__ in,
                                               const float* __restrict__ dep,
                                               const float* __restrict__ oth,
                                               float* __restrict__ G,
                                               float* __restrict__ E0,
                                               float* __restrict__ Ec) {
    const int i = blockIdx.x;
    const int b = blockIdx.y;
    const int tid = threadIdx.x;
    for (int rep = 0; rep < 2; ++rep) {
        const int j = tid + rep * 256;
        float g = 0.0f;
        for (int h = 0; h < H; ++h) {
            float x = in[(((size_t)(b * H + h) * N + i) * N) + j];
            float m = (i == 0) ? dep[b * H + h] : oth[b * N + i];
            float e = __expf(x - m);
            g += e;
            if (i == 0) E0[(b * H + h) * N + j] = e;
            if (j == 0) Ec[(b * H + h) * N + i] = e;
        }
        G[((size_t)(b * N) + i) * N + j] = g;
    }
}

// Odd (row) iteration: r[b,i] = 1 / (sum_h Ec*c0 + sum_{j>=1} G*c);  r0[b,h] similar from E0.
__global__ __launch_bounds__(256) void k_row_iter(const float* __restrict__ G,
                                                  const float* __restrict__ E0,
                                                  const float* __restrict__ Ec,
                                                  const float* __restrict__ c0v,
                                                  const float* __restrict__ cv,
                                                  float* __restrict__ r0v,
                                                  float* __restrict__ rv) {
    const int i = blockIdx.x;
    const int b = blockIdx.y;
    const int tid = threadIdx.x;
    if (i > 0) {
        __shared__ float red[256];
        const float* grow = G + ((size_t)(b * N) + i) * N;
        const float* crow = cv + b * N;
        float p = 0.0f;
        for (int j = tid; j < N; j += 256)
            if (j > 0) p += grow[j] * crow[j];
        red[tid] = p; __syncthreads();
        for (int s = 128; s > 0; s >>= 1) {
            if (tid < s) red[tid] += red[tid + s];
            __syncthreads();
        }
        if (tid == 0) {
            float ssum = red[0];
            for (int h = 0; h < H; ++h) ssum += Ec[(b * H + h) * N + i] * c0v[b * H + h];
            rv[b * N + i] = 1.0f / ssum;
        }
    } else {
        const int h = tid >> 5, lane = tid & 31;
        const float* erow = E0 + (b * H + h) * N;
        const float* crow = cv + b * N;
        float p = 0.0f;
        for (int j = lane; j < N; j += 32)
            if (j > 0) p += erow[j] * crow[j];
        for (int s = 16; s > 0; s >>= 1) p += __shfl_down(p, s, 32);
        if (lane == 0) {
            float ssum = p + Ec[(b * H + h) * N + 0] * c0v[b * H + h];  // E00 * c0
            r0v[b * H + h] = 1.0f / ssum;
        }
    }
}

// Even (col) iteration: c[b,j] = 1 / (sum_h E0*r0 + sum_{i>=1} G*r);  c0[b,h] from Ec.
__global__ __launch_bounds__(256) void k_col_iter(const float* __restrict__ G,
                                                  const float* __restrict__ E0,
                                                  const float* __restrict__ Ec,
                                                  const float* __restrict__ r0v,
                                                  const float* __restrict__ rv,
                                                  float* __restrict__ c0v,
                                                  float* __restrict__ cv) {
    const int t = blockIdx.x;  // 0..7 = j-tiles, 8 = c0 block
    const int b = blockIdx.y;
    const int tid = threadIdx.x;
    if (t < 8) {
        __shared__ float rsh[N];
        __shared__ float red[256];
        rsh[tid] = rv[b * N + tid];
        rsh[tid + 256] = rv[b * N + tid + 256];
        __syncthreads();
        const int j0 = t * 64;
        const int tj = tid & 63, ti = tid >> 6;
        float acc = 0.0f;
        for (int i = 1 + ti; i < N; i += 4)
            acc += G[((size_t)(b * N) + i) * N + j0 + tj] * rsh[i];
        red[tid] = acc; __syncthreads();
        if (tid < 64) {
            const int j = j0 + tid;
            float ssum = red[tid] + red[tid + 64] + red[tid + 128] + red[tid + 192];
            for (int h = 0; h < H; ++h) ssum += E0[(b * H + h) * N + j] * r0v[b * H + h];
            if (j > 0) cv[b * N + j] = 1.0f / ssum;
        }
    } else {
        const int h = tid >> 5, lane = tid & 31;
        const float* ecol = Ec + (b * H + h) * N;
        const float* rrow = rv + b * N;
        float p = 0.0f;
        for (int i = lane; i < N; i += 32)
            if (i > 0) p += ecol[i] * rrow[i];
        for (int s = 16; s > 0; s >>= 1) p += __shfl_down(p, s, 32);
        if (lane == 0) {
            float ssum = p + ecol[0] * r0v[b * H + h];  // E00 * r0
            c0v[b * H + h] = 1.0f / ssum;
        }
    }
}

__global__ __launch_bounds__(256) void k_final(const float* __restrict__ in,
                                               const float* __restrict__ dep,
                                               const float* __restrict__ oth,
                                               const float* __restrict__ r0v,
                                               const float* __restrict__ rv,
                                               const float* __restrict__ c0v,
                                               const float* __restrict__ cv,
                                               float* __restrict__ out) {
    const size_t v = (size_t)blockIdx.x * 256 + threadIdx.x;  // float4 index
    const int j4 = (int)(v & 127);
    size_t rest = v >> 7;
    const int i = (int)(rest & 511); rest >>= 9;
    const int h = (int)(rest & 7);
    const int b = (int)(rest >> 3);
    const float m = (i == 0) ? dep[b * H + h] : oth[b * N + i];
    const float R = (i == 0) ? r0v[b * H + h] : rv[b * N + i];
    const float4 x = reinterpret_cast<const float4*>(in)[v];
    const int j = j4 * 4;
    const float* crow = cv + b * N;
    const float cx = (j == 0) ? c0v[b * H + h] : crow[j];
    float4 o;
    o.x = __expf(x.x - m) * R * cx;
    o.y = __expf(x.y - m) * R * crow[j + 1];
    o.z = __expf(x.z - m) * R * crow[j + 2];
    o.w = __expf(x.w - m) * R * crow[j + 3];
    reinterpret_cast<float4*>(out)[v] = o;
}

extern "C" void kernel_launch(void* const* d_in, const int* in_sizes, int n_in,
                              void* d_out, int out_size, void* d_ws, size_t ws_size,
                              hipStream_t stream) {
    (void)in_sizes; (void)n_in; (void)out_size; (void)ws_size;
    const float* in = (const float*)d_in[0];
    float* out = (float*)d_out;
    float* ws = (float*)d_ws;

    float* dep = ws;               // B*H
    float* oth = dep + B * H;      // B*N
    float* r0v = oth + B * N;      // B*H
    float* c0v = r0v + B * H;      // B*H
    float* rv  = c0v + B * H;      // B*N
    float* cv  = rv + B * N;       // B*N
    float* E0  = cv + B * N;       // B*H*N
    float* Ec  = E0 + B * H * N;   // B*H*N
    float* G   = out;              // first B*N*N floats of d_out as scratch (overwritten by k_final)

    dim3 gridBN(N, B);
    k_max_init<<<gridBN, 256, 0, stream>>>(in, dep, oth, c0v, cv, rv);
    k_build<<<gridBN, 256, 0, stream>>>(in, dep, oth, G, E0, Ec);
    for (int it = 0; it < 5; ++it) {
        k_row_iter<<<gridBN, 256, 0, stream>>>(G, E0, Ec, c0v, cv, r0v, rv);
        k_col_iter<<<dim3(9, B), 256, 0, stream>>>(G, E0, Ec, r0v, rv, c0v, cv);
    }
    const int nblk_final = (B * H * N * N / 4) / 256;  // 65536
    k_final<<<nblk_final, 256, 0, stream>>>(in, dep, oth, r0v, rv, c0v, cv, out);
}

// Round 2
// 365.346 us; speedup vs baseline: 1.4406x; 1.4406x over previous
//
#include <hip/hip_runtime.h>
#include <hip/hip_cooperative_groups.h>
#include <math.h>

namespace cg = cooperative_groups;

#define B 32
#define H 8
#define N 512
#define NBLK 256   // cooperative blocks (1 per CU)
#define TPB 512
#define RPB 64     // G rows per cooperative block
// d_out tail scratch layout (floats):
#define OFF_E0   8388608           // B*N*N
#define OFF_EC   (OFF_E0 + 131072)
#define OFF_PA   (OFF_EC + 131072)
#define OFF_PB   (OFF_PA + 131072)
#define OFF_C0A  (OFF_PB + 131072)
#define OFF_C0B  (OFF_C0A + 2048)

// Build G[b,i,j] = sum_h exp(x[b,h,i,j]); E0[b,h,j] = exp(x[b,h,0,j]); Ec[b,h,i] = exp(x[b,h,i,0]).
// No max subtraction: per-group constants cancel exactly in the first normalization.
__global__ __launch_bounds__(256) void k_build(const float* __restrict__ in,
                                               float* __restrict__ G,
                                               float* __restrict__ E0,
                                               float* __restrict__ Ec) {
    const int i = blockIdx.x;
    const int b = blockIdx.y;
    const int tid = threadIdx.x;
    for (int rep = 0; rep < 2; ++rep) {
        const int j = tid + rep * 256;
        float g = 0.0f;
        for (int h = 0; h < H; ++h) {
            float x = in[(((size_t)(b * H + h) * N + i) * N) + j];
            float e = __expf(x);
            g += e;
            if (i == 0) E0[(b * H + h) * N + j] = e;
            if (j == 0) Ec[(b * H + h) * N + i] = e;
        }
        G[((size_t)(b * N) + i) * N + j] = g;
    }
}

// 5 x (row-normalize, col-normalize) with G LDS-resident. Block blk: b = blk>>3, owns rows
// [g*64, g*64+64) of G[b]; additionally owns head h=g for the E0/r0 work.
// Column sums via double-buffered per-block partials (no atomics, no zeroing).
__global__ __launch_bounds__(TPB) void k_coop(const float* __restrict__ G,
                                              const float* __restrict__ E0,
                                              const float* __restrict__ Ec,
                                              float* __restrict__ partA,
                                              float* __restrict__ partB,
                                              float* __restrict__ c0pA,
                                              float* __restrict__ c0pB,
                                              float* __restrict__ rv,
                                              float* __restrict__ r0v,
                                              float* __restrict__ cv,
                                              float* __restrict__ c0v) {
    cg::grid_group grid = cg::this_grid();
    __shared__ float Gs[RPB][N];   // 128 KB
    __shared__ float E0g[N];       // this block's head (h=g) row-0 slice
    __shared__ float vec[N];       // c values (row phase)
    __shared__ float EcS[H][RPB];  // Ec for owned rows
    __shared__ float rloc[RPB];
    __shared__ float c0rec[H];
    __shared__ float r0loc_s;

    const int blk = blockIdx.x;
    const int b = blk >> 3;
    const int g = blk & 7;
    const int rbase = g * RPB;
    const bool owner = (g == 0);
    const int tid = threadIdx.x;
    const int w = tid >> 6, lane = tid & 63;

    // ---- load LDS-resident state ----
    {
        const float4* Gg = reinterpret_cast<const float4*>(G + ((size_t)(b * N) + rbase) * N);
        float4* Gl = reinterpret_cast<float4*>(&Gs[0][0]);
        for (int t = tid; t < RPB * N / 4; t += TPB) Gl[t] = Gg[t];
    }
    for (int t = tid; t < H * RPB; t += TPB)
        EcS[t / RPB][t % RPB] = Ec[(b * H + (t / RPB)) * N + rbase + (t % RPB)];
    if (tid < N) E0g[tid] = E0[(b * H + g) * N + tid];
    const float E00g = Ec[(b * H + g) * N];  // E[b,g,0,0]
    __syncthreads();

    float* parts[2] = {partA, partB};
    float* c0ps[2] = {c0pA, c0pB};

    for (int it = 0; it < 5; ++it) {
        // ---------- row phase: r[b,i] and r0[b,h] ----------
        if (it == 0) {
            vec[tid] = (tid == 0) ? 0.0f : 1.0f;  // c = 1; j=0 masked (handled via c0 term)
            if (tid < H) c0rec[tid] = 1.0f;
        } else {
            const float* p = parts[it & 1] + (size_t)b * 8 * N;
            float cs = 0.0f;
#pragma unroll
            for (int gg = 0; gg < 8; ++gg) cs += p[gg * N + tid];
            vec[tid] = (tid == 0) ? 0.0f : 1.0f / cs;
            if (tid < H) {
                const float* q = c0ps[it & 1] + b * 8 * H;
                float s = 0.0f;
#pragma unroll
                for (int gg = 0; gg < 8; ++gg) s += q[gg * H + tid];
                c0rec[tid] = 1.0f / s;
            }
        }
        __syncthreads();
        float cj[8];
#pragma unroll
        for (int k = 0; k < 8; ++k) cj[k] = vec[lane + 64 * k];
        for (int r8 = 0; r8 < 8; ++r8) {
            const int il = w * 8 + r8;
            float pacc = 0.0f;
#pragma unroll
            for (int k = 0; k < 8; ++k) pacc += Gs[il][lane + 64 * k] * cj[k];
#pragma unroll
            for (int s = 32; s > 0; s >>= 1) pacc += __shfl_down(pacc, s, 64);
            if (lane == 0) {
                float s2 = pacc;
#pragma unroll
                for (int h = 0; h < H; ++h) s2 += EcS[h][il] * c0rec[h];
                float rva = 1.0f / s2;
                rloc[il] = rva;
                rv[b * N + rbase + il] = rva;
            }
        }
        // r0 for head h=g (one wave per block)
        if (w == g) {
            float pacc = 0.0f;
#pragma unroll
            for (int k = 0; k < 8; ++k) pacc += E0g[lane + 64 * k] * cj[k];
#pragma unroll
            for (int s = 32; s > 0; s >>= 1) pacc += __shfl_down(pacc, s, 64);
            if (lane == 0) {
                float v = 1.0f / (pacc + E00g * c0rec[g]);
                r0loc_s = v;
                r0v[b * H + g] = v;
            }
        }
        __syncthreads();
        // ---------- col phase: partial column sums ----------
        {
            const float r0l = r0loc_s;
            float acc = 0.0f;
            const int il0 = owner ? 1 : 0;  // owner's local row 0 is global row 0 (handled via E0)
#pragma unroll 4
            for (int il = il0; il < RPB; ++il) acc += Gs[il][tid] * rloc[il];
            acc += E0g[tid] * r0l;  // head h=g's i=0 contribution
            parts[(it + 1) & 1][((size_t)(b * 8) + g) * N + tid] = acc;
            // c0 partials: wave w handles head h=w over owned rows
            float q = EcS[w][lane] * ((owner && lane == 0) ? 0.0f : rloc[lane]);
            if (w == g && lane == 0) q += E00g * r0l;  // i=0 term for head g
#pragma unroll
            for (int s = 32; s > 0; s >>= 1) q += __shfl_down(q, s, 64);
            if (lane == 0) c0ps[(it + 1) & 1][(b * 8 + g) * H + w] = q;
        }
        grid.sync();
    }
    // ---- finalize c factors (block g==0 of each b) ----
    if (owner) {
        const float* p = parts[1] + (size_t)b * 8 * N;  // (4+1)&1 == 1
        float cs = 0.0f;
#pragma unroll
        for (int gg = 0; gg < 8; ++gg) cs += p[gg * N + tid];
        cv[b * N + tid] = (tid == 0) ? 1.0f : 1.0f / cs;
        if (tid < H) {
            const float* q = c0ps[1] + b * 8 * H;
            float s = 0.0f;
#pragma unroll
            for (int gg = 0; gg < 8; ++gg) s += q[gg * H + tid];
            c0v[b * H + tid] = 1.0f / s;
        }
    }
}

__global__ __launch_bounds__(256) void k_final(const float* __restrict__ in,
                                               const float* __restrict__ rv,
                                               const float* __restrict__ r0v,
                                               const float* __restrict__ cv,
                                               const float* __restrict__ c0v,
                                               float* __restrict__ out) {
    const size_t v = (size_t)blockIdx.x * 256 + threadIdx.x;  // float4 index
    const int j4 = (int)(v & 127);
    size_t rest = v >> 7;
    const int i = (int)(rest & 511); rest >>= 9;
    const int h = (int)(rest & 7);
    const int b = (int)(rest >> 3);
    const float R = (i == 0) ? r0v[b * H + h] : rv[b * N + i];
    const float4 x = reinterpret_cast<const float4*>(in)[v];
    float4 cl = reinterpret_cast<const float4*>(cv + b * N)[j4];
    if (j4 == 0) cl.x = c0v[b * H + h];
    float4 o;
    o.x = __expf(x.x) * R * cl.x;
    o.y = __expf(x.y) * R * cl.y;
    o.z = __expf(x.z) * R * cl.z;
    o.w = __expf(x.w) * R * cl.w;
    reinterpret_cast<float4*>(out)[v] = o;
}

extern "C" void kernel_launch(void* const* d_in, const int* in_sizes, int n_in,
                              void* d_out, int out_size, void* d_ws, size_t ws_size,
                              hipStream_t stream) {
    (void)in_sizes; (void)n_in; (void)out_size; (void)ws_size;
    const float* in = (const float*)d_in[0];
    float* out = (float*)d_out;
    float* ws = (float*)d_ws;

    // persistent factor vectors (must survive into k_final) live in ws
    float* rv  = ws;           // B*N
    float* cv  = ws + 16384;   // B*N
    float* r0v = ws + 32768;   // B*H
    float* c0v = ws + 33024;   // B*H

    // pre-final scratch lives in the tail of d_out (fully consumed before k_final writes)
    float* G   = out;             // B*N*N
    float* E0  = out + OFF_E0;    // B*H*N
    float* Ec  = out + OFF_EC;    // B*H*N
    float* pA  = out + OFF_PA;    // B*8*N
    float* pB  = out + OFF_PB;    // B*8*N
    float* c0A = out + OFF_C0A;   // B*8*H
    float* c0B = out + OFF_C0B;   // B*8*H

    k_build<<<dim3(N, B), 256, 0, stream>>>(in, G, E0, Ec);

    void* args[] = {(void*)&G, (void*)&E0, (void*)&Ec, (void*)&pA, (void*)&pB,
                    (void*)&c0A, (void*)&c0B, (void*)&rv, (void*)&r0v,
                    (void*)&cv, (void*)&c0v};
    hipLaunchCooperativeKernel(reinterpret_cast<void*>(k_coop), dim3(NBLK), dim3(TPB),
                               args, 0, stream);

    k_final<<<65536, 256, 0, stream>>>(in, rv, r0v, cv, c0v, out);
}